// Round 5
// baseline (147.962 us; speedup 1.0000x reference)
//
#include <hip/hip_runtime.h>
#include <math.h>

// Problem constants
#define NN 512
#define DD 512
#define NPAIRS 130816            // 512*511/2
#define TYPES_OFF 0              // [P,10] floats
#define ARGMAX_OFF 1308160      // [P] floats
#define STRENGTH_OFF 1438976    // [P] floats

// fp32 fast-path argmax guard: recompute logits in fp64 when fp32 top-2 gap
// is below this. fp32-path worst-case abs error ~5e-5; realistic rms ~1e-6.
#define GAP_THRESH 2.5e-4f

// ws layout (byte offsets) — classifier K-split-4, strength K-split-2:
//   ca0..ca3 double[512][512] @ 0, 2097152, 4194304, 6291456    (A-part quarters; cb1 folded into q0)
//   cb0..cb3 double[512][512] @ 8388608, 10485760, 12582912, 14680064  (B-part quarters)
//   sa0  float [512][256] @ 16777216   (bias sb1 folded)
//   sa1  float [512][256] @ 17301504
//   sb0  float [512][256] @ 17825792
//   sbp1 float [512][256] @ 18350080
//   cfa  float [512][512] @ 18874368   (= (float)Σca, combine_kernel)
//   cfb  float [512][512] @ 19922944
//   sfa  float [512][256] @ 20971520   (= sa0+sa1)
//   sfb  float [512][256] @ 21495808
// total 22,020,096 bytes
//
// LESSONS LEDGER:
//  R2a: narrower proj n-tiles INCREASE total operand traffic (proj is
//       L1/L2-latency-bound on redundant loads) — keep 8x64 wave tile.
//       K-SPLIT adds occupancy WITHOUT operand duplication (this round).
//  R2b: no inline asm with "s" constraints in pair loop — scalar
//       materialization + sched fences (VALUBusy 43->26%).
//  R3:  __launch_bounds__(256,6) on pair -> VGPR squeeze -> 217 MB scratch
//       spill traffic (dur 2.5x). Keep (256,4).
//  R4:  combine_kernel pre-sums K-split partials once (pair staging had been
//       re-summing fp64 partials ~128x/element). pair now <42us. WORKED.
//  R5:  proj was 3 blocks/CU (768 grid), ~30us stall. Classifier K-split 4
//       -> 1280 blocks = 5/CU (this round).

__device__ __forceinline__ void fma64_step(
    const float4& a0, const float4& a1,
    const float4& b0, const float4& b1, const float4& b2, const float4& b3,
    double acc[2][4])
{
    const float av[2][4] = {{a0.x,a0.y,a0.z,a0.w},{a1.x,a1.y,a1.z,a1.w}};
    const float bv[4][4] = {{b0.x,b0.y,b0.z,b0.w},{b1.x,b1.y,b1.z,b1.w},
                            {b2.x,b2.y,b2.z,b2.w},{b3.x,b3.y,b3.z,b3.w}};
    #pragma unroll
    for (int kk = 0; kk < 4; ++kk) {
        double ad0 = (double)av[0][kk], ad1 = (double)av[1][kk];
        #pragma unroll
        for (int c = 0; c < 4; ++c) {
            double bd = (double)bv[kk][c];
            acc[0][c] = fma(ad0, bd, acc[0][c]);
            acc[1][c] = fma(ad1, bd, acc[1][c]);
        }
    }
}

__device__ __forceinline__ void fma32_step(
    const float4& a0, const float4& a1,
    const float4& b0, const float4& b1, const float4& b2, const float4& b3,
    float acc[2][4])
{
    const float av[2][4] = {{a0.x,a0.y,a0.z,a0.w},{a1.x,a1.y,a1.z,a1.w}};
    const float bv[4][4] = {{b0.x,b0.y,b0.z,b0.w},{b1.x,b1.y,b1.z,b1.w},
                            {b2.x,b2.y,b2.z,b2.w},{b3.x,b3.y,b3.z,b3.w}};
    #pragma unroll
    for (int kk = 0; kk < 4; ++kk) {
        #pragma unroll
        for (int c = 0; c < 4; ++c) {
            acc[0][c] = fmaf(av[0][kk], bv[kk][c], acc[0][c]);
            acc[1][c] = fmaf(av[1][kk], bv[kk][c], acc[1][c]);
        }
    }
}

// Barrier-free, LDS-free, atomic-free projection GEMM.
// Classifier: wave = 8m x 64n tile, K-split 4 (quarter = 128 k) -> 4096 waves.
//   Block = one (mt,nt) tile x 4 quarters (B-col locality within block).
// Strength:   wave = 8m x 64n tile, K-split 2 -> 1024 waves.
// Grid 1280 blocks = 5 blocks/CU (proj was latency-stalled at 3/CU).
__global__ __launch_bounds__(256, 4) void proj_kernel(
    const float* __restrict__ F, const float* __restrict__ cw1,
    const float* __restrict__ sw1,
    const float* __restrict__ cb1, const float* __restrict__ sb1,
    double* __restrict__ ca0, double* __restrict__ ca1,
    double* __restrict__ ca2, double* __restrict__ ca3,
    double* __restrict__ cb0, double* __restrict__ cb1p,
    double* __restrict__ cb2p, double* __restrict__ cb3p,
    float* __restrict__ sa0, float* __restrict__ sa1,
    float* __restrict__ sb0, float* __restrict__ sbp1)
{
    const int t = threadIdx.x;
    const int wid  = blockIdx.x * 4 + (t >> 6);
    const int lane = t & 63;
    const int mg = lane >> 4;              // 0..3  (2-row group)
    const int nq = lane & 15;              // 0..15 (4-col group)

    if (wid < 4096) {
        // ---------------- fp64 classifier projection, K-split 4 ----------------
        const int z  = wid & 3;            // K quarter (== wave id in block)
        const int r  = wid >> 2;           // 0..1023 (== blockIdx)
        const int nt = r & 15;             // 64-col tile over 1024
        const int mt = r >> 4;             // 0..63
        const int m0 = mt * 8;
        const int n  = nt * 64;
        const float* W = (n < 512) ? cw1 : cw1 + 512 * 512;
        const int n0   = (n < 512) ? n : n - 512;
        double* outp;
        if (n < 512) outp = (z == 0) ? ca0 : (z == 1) ? ca1 : (z == 2) ? ca2 : ca3;
        else         outp = (z == 0) ? cb0 : (z == 1) ? cb1p : (z == 2) ? cb2p : cb3p;
        const bool addbias = (z == 0) && (n < 512);

        const int row0 = m0 + mg * 2;
        const int col0 = n0 + nq * 4;
        const float* pa0 = F + row0 * 512 + z * 128;
        const float* pa1 = pa0 + 512;
        const float* pb  = W + (z * 128) * 512 + col0;

        double acc[2][4];
        #pragma unroll
        for (int rr = 0; rr < 2; ++rr)
            #pragma unroll
            for (int cc = 0; cc < 4; ++cc) acc[rr][cc] = 0.0;

        float4 a0 = *(const float4*)(pa0);
        float4 a1 = *(const float4*)(pa1);
        float4 b0 = *(const float4*)(pb);
        float4 b1 = *(const float4*)(pb + 512);
        float4 b2 = *(const float4*)(pb + 1024);
        float4 b3 = *(const float4*)(pb + 1536);
        for (int s = 0; s < 31; ++s) {     // 32 k4-steps, software-pipelined
            float4 na0 = *(const float4*)(pa0 + (s + 1) * 4);
            float4 na1 = *(const float4*)(pa1 + (s + 1) * 4);
            const float* nb = pb + (s + 1) * 2048;
            float4 nb0 = *(const float4*)(nb);
            float4 nb1 = *(const float4*)(nb + 512);
            float4 nb2 = *(const float4*)(nb + 1024);
            float4 nb3 = *(const float4*)(nb + 1536);
            fma64_step(a0, a1, b0, b1, b2, b3, acc);
            a0 = na0; a1 = na1; b0 = nb0; b1 = nb1; b2 = nb2; b3 = nb3;
        }
        fma64_step(a0, a1, b0, b1, b2, b3, acc);

        #pragma unroll
        for (int rr = 0; rr < 2; ++rr) {
            double v[4];
            #pragma unroll
            for (int cc = 0; cc < 4; ++cc) {
                v[cc] = acc[rr][cc];
                if (addbias) v[cc] += (double)cb1[col0 + cc];
            }
            double* dst = outp + (row0 + rr) * 512 + col0;
            *(double2*)(dst + 0) = make_double2(v[0], v[1]);
            *(double2*)(dst + 2) = make_double2(v[2], v[3]);
        }
    } else {
        // ---------------- fp32 strength projection (K-split 2) ----------------
        const int w2 = wid - 4096;
        const int z  = w2 & 1;
        const int r  = w2 >> 1;            // 0..511
        const int nt = r & 7;              // 64-col tile over 512
        const int mt = r >> 3;             // 0..63
        const int m0 = mt * 8;
        const int n  = nt * 64;
        const float* W = (n < 256) ? sw1 : sw1 + 512 * 256;
        const int n0   = (n < 256) ? n : n - 256;
        float* outp    = (n < 256) ? (z ? sa1 : sa0) : (z ? sbp1 : sb0);
        const bool addbias = (z == 0) && (n < 256);

        const int row0 = m0 + mg * 2;
        const int col0 = n0 + nq * 4;
        const float* pa0 = F + row0 * 512 + z * 256;
        const float* pa1 = pa0 + 512;
        const float* pb  = W + (z * 256) * 256 + col0;

        float acc[2][4];
        #pragma unroll
        for (int rr = 0; rr < 2; ++rr)
            #pragma unroll
            for (int cc = 0; cc < 4; ++cc) acc[rr][cc] = 0.f;

        float4 a0 = *(const float4*)(pa0);
        float4 a1 = *(const float4*)(pa1);
        float4 b0 = *(const float4*)(pb);
        float4 b1 = *(const float4*)(pb + 256);
        float4 b2 = *(const float4*)(pb + 512);
        float4 b3 = *(const float4*)(pb + 768);
        for (int s = 0; s < 63; ++s) {
            float4 na0 = *(const float4*)(pa0 + (s + 1) * 4);
            float4 na1 = *(const float4*)(pa1 + (s + 1) * 4);
            const float* nb = pb + (s + 1) * 1024;
            float4 nb0 = *(const float4*)(nb);
            float4 nb1 = *(const float4*)(nb + 256);
            float4 nb2 = *(const float4*)(nb + 512);
            float4 nb3 = *(const float4*)(nb + 768);
            fma32_step(a0, a1, b0, b1, b2, b3, acc);
            a0 = na0; a1 = na1; b0 = nb0; b1 = nb1; b2 = nb2; b3 = nb3;
        }
        fma32_step(a0, a1, b0, b1, b2, b3, acc);

        #pragma unroll
        for (int rr = 0; rr < 2; ++rr) {
            float4 v = make_float4(acc[rr][0], acc[rr][1], acc[rr][2], acc[rr][3]);
            if (addbias) {
                v.x += sb1[col0 + 0]; v.y += sb1[col0 + 1];
                v.z += sb1[col0 + 2]; v.w += sb1[col0 + 3];
            }
            *(float4*)(outp + (row0 + rr) * 256 + col0) = v;
        }
    }
}

// Pre-sum the K-split partials ONCE. cfa/cfb = (float)(Σ classifier quarters),
// sfa/sfb = sa0+sa1 etc. ~18 MB read, 3 MB write.
__global__ __launch_bounds__(256) void combine_kernel(
    const double* __restrict__ ca0, const double* __restrict__ ca1,
    const double* __restrict__ ca2, const double* __restrict__ ca3,
    const double* __restrict__ cb0, const double* __restrict__ cb1p,
    const double* __restrict__ cb2p, const double* __restrict__ cb3p,
    const float* __restrict__ sa0, const float* __restrict__ sa1,
    const float* __restrict__ sb0, const float* __restrict__ sbp1,
    float* __restrict__ cfa, float* __restrict__ cfb,
    float* __restrict__ sfa, float* __restrict__ sfb)
{
    const int t = blockIdx.x * 256 + threadIdx.x;     // 0..131071 (512 blocks)
    {   // classifier: double2 unit t of each array (131072 units = 512*512 ele)
        const int e = 2 * t;
        double2 x0 = *(const double2*)(ca0 + e);
        double2 x1 = *(const double2*)(ca1 + e);
        double2 x2 = *(const double2*)(ca2 + e);
        double2 x3 = *(const double2*)(ca3 + e);
        *(float2*)(cfa + e) = make_float2(
            (float)((x0.x + x1.x) + (x2.x + x3.x)),
            (float)((x0.y + x1.y) + (x2.y + x3.y)));
        double2 y0 = *(const double2*)(cb0 + e);
        double2 y1 = *(const double2*)(cb1p + e);
        double2 y2 = *(const double2*)(cb2p + e);
        double2 y3 = *(const double2*)(cb3p + e);
        *(float2*)(cfb + e) = make_float2(
            (float)((y0.x + y1.x) + (y2.x + y3.x)),
            (float)((y0.y + y1.y) + (y2.y + y3.y)));
    }
    if (t < 65536) {   // strength: float4 units (32768 per array)
        const bool second = t >= 32768;
        const int e = (second ? (t - 32768) : t) * 4;
        const float* s0 = second ? sb0 : sa0;
        const float* s1 = second ? sbp1 : sa1;
        float* dst      = second ? sfb : sfa;
        float4 a = *(const float4*)(s0 + e);
        float4 b = *(const float4*)(s1 + e);
        *(float4*)(dst + e) = make_float4(a.x + b.x, a.y + b.y, a.z + b.z, a.w + b.w);
    }
}

// Pair phase: block = 8x8 pair tile, 4 waves = 4 K-quarters, LDS combine.
// Grid: 2080 triangular tiles. Staging is a pure float4 copy from the
// pre-summed cfa/cfb/sfa/sfb. Inner loops read LDS as float4 with
// k-sequential scalar fmaf per channel.
// Argmax exactness preserved by the fp64 cooperative recheck (reads the 8
// fp64 quarter-partials) of pairs whose fp32 top-2 gap < GAP_THRESH.
// NOTE: __launch_bounds__(256,4) — (256,6) spilled 217 MB of scratch (R3).
__global__ __launch_bounds__(256, 4) void pair_kernel(
    const double* __restrict__ ca0, const double* __restrict__ ca1,
    const double* __restrict__ ca2, const double* __restrict__ ca3,
    const double* __restrict__ cb0, const double* __restrict__ cb1p,
    const double* __restrict__ cb2p, const double* __restrict__ cb3p,
    const float* __restrict__ cfa, const float* __restrict__ cfb,
    const float* __restrict__ sfa, const float* __restrict__ sfb,
    const float* __restrict__ cw2, const float* __restrict__ cb2,
    const float* __restrict__ sw2, const float* __restrict__ sb2,
    float* __restrict__ out)
{
    // triangular tile decode: S(bi) = bi*(129-bi)/2
    const int b = blockIdx.x;
    int bi = (int)floorf((129.0f - sqrtf(16641.0f - 8.0f * (float)b)) * 0.5f);
    while ((bi + 1) * (129 - (bi + 1)) / 2 <= b) ++bi;
    while (bi * (129 - bi) / 2 > b) --bi;
    const int bj = bi + (b - bi * (129 - bi) / 2);
    const int i0 = bi * 8, j0 = bj * 8;

    const int t = threadIdx.x;
    const int q  = t >> 6;                               // K-quarter = wave id
    const int qu = __builtin_amdgcn_readfirstlane(q);    // wave-uniform -> s_load bases
    const int l = t & 63;
    const int pi = l >> 3, pj = l & 7;
    const int i = i0 + pi, j = j0 + pj;

    __shared__ __align__(16) float smem[4352];      // 17408 B
    float* sSa = smem;                              // [4*8][68] strength stage
    float* sSb = smem + 2176;
    float* sA  = smem;                              // [4*8][68] classifier stage
    float* sB  = smem + 2176;
    float* lgbuf = smem;                            // [3][64][10]
    float* stbuf = smem + 1920;                     // [3][64]

    // ---------------- strength (fp32), K=64 per quarter ----------------
    #pragma unroll
    for (int u = 0; u < 4; ++u) {
        int idx = u * 256 + t;
        int kq  = idx & 15;
        int row = (idx >> 4) & 7;
        int qq  = (idx >> 7) & 3;
        int arr = idx >> 9;
        int off = (arr ? (j0 + row) : (i0 + row)) * 256 + qq * 64 + kq * 4;
        const float* src = arr ? sfb : sfa;
        float4 v = *(const float4*)(src + off);
        float* dst = (arr ? sSb : sSa) + (qq * 8 + row) * 68 + kq * 4;
        *(float4*)dst = v;
    }
    __syncthreads();
    float accs = 0.f;
    {
        const float* sw2q = sw2 + qu * 64;
        const float* ra = sSa + (q * 8 + pi) * 68;
        const float* rb = sSb + (q * 8 + pj) * 68;
        // 4 partial accumulators break the serial fma chain (strength output
        // has 0.0156 abs tolerance; reassociation safe — argmax unaffected)
        float p0 = 0.f, p1 = 0.f, p2 = 0.f, p3 = 0.f;
        for (int kk = 0; kk < 64; kk += 4) {
            float4 a4 = *(const float4*)(ra + kk);
            float4 b4 = *(const float4*)(rb + kk);
            p0 = fmaf(fmaxf(a4.x + b4.x, 0.f), sw2q[kk + 0], p0);
            p1 = fmaf(fmaxf(a4.y + b4.y, 0.f), sw2q[kk + 1], p1);
            p2 = fmaf(fmaxf(a4.z + b4.z, 0.f), sw2q[kk + 2], p2);
            p3 = fmaf(fmaxf(a4.w + b4.w, 0.f), sw2q[kk + 3], p3);
        }
        accs = (p0 + p1) + (p2 + p3);
    }

    // ---------------- classifier (fp32 fast path), K=128 per quarter ----------------
    float lg[10];
    #pragma unroll
    for (int c = 0; c < 10; ++c) lg[c] = 0.f;

    for (int rnd = 0; rnd < 2; ++rnd) {
        __syncthreads();   // prior reads of sA/sB (or sSa/sSb) done
        // stage 64 k per quarter: pure float4 copy from pre-summed arrays
        #pragma unroll
        for (int u = 0; u < 4; ++u) {
            int idx = u * 256 + t;
            int kq  = idx & 15;               // 16 groups of 4 k
            int row = (idx >> 4) & 7;
            int qq  = (idx >> 7) & 3;
            int arr = idx >> 9;
            int off = (arr ? (j0 + row) : (i0 + row)) * 512 + qq * 128 + rnd * 64 + kq * 4;
            const float* src = arr ? cfb : cfa;
            float4 v = *(const float4*)(src + off);
            float* dst = (arr ? sB : sA) + (qq * 8 + row) * 68 + kq * 4;
            *(float4*)dst = v;
        }
        __syncthreads();
        const float* ra = sA + (q * 8 + pi) * 68;
        const float* rb = sB + (q * 8 + pj) * 68;
        const float* wr = cw2 + (qu * 128 + rnd * 64) * 10;
        for (int kk = 0; kk < 64; kk += 4) {
            float4 ra4 = *(const float4*)(ra + kk);    // ds_read_b128
            float4 rb4 = *(const float4*)(rb + kk);
            float h0 = fmaxf(ra4.x + rb4.x, 0.f);
            float h1 = fmaxf(ra4.y + rb4.y, 0.f);
            float h2 = fmaxf(ra4.z + rb4.z, 0.f);
            float h3 = fmaxf(ra4.w + rb4.w, 0.f);
            const float* w = wr + kk * 10;
            #pragma unroll
            for (int c = 0; c < 10; ++c) lg[c] = fmaf(h0, w[c], lg[c]);
            #pragma unroll
            for (int c = 0; c < 10; ++c) lg[c] = fmaf(h1, w[10 + c], lg[c]);
            #pragma unroll
            for (int c = 0; c < 10; ++c) lg[c] = fmaf(h2, w[20 + c], lg[c]);
            #pragma unroll
            for (int c = 0; c < 10; ++c) lg[c] = fmaf(h3, w[30 + c], lg[c]);
        }
    }

    // ---------------- combine via LDS ----------------
    __syncthreads();
    if (q > 0) {
        float* dst = lgbuf + ((q - 1) * 64 + l) * 10;
        #pragma unroll
        for (int c = 0; c < 10; ++c) dst[c] = lg[c];
        stbuf[(q - 1) * 64 + l] = accs;
    }
    __syncthreads();
    if (q == 0) {
        #pragma unroll
        for (int w = 0; w < 3; ++w) {
            const float* srcb = lgbuf + (w * 64 + l) * 10;
            #pragma unroll
            for (int c = 0; c < 10; ++c) lg[c] += srcb[c];
        }
        float st = accs + stbuf[l] + stbuf[64 + l] + stbuf[128 + l] + sb2[0];

        #pragma unroll
        for (int c = 0; c < 10; ++c) lg[c] += cb2[c];

        // fp32 argmax + top-2 gap
        float mx = lg[0], mx2 = -3.0e38f; int am2 = 0;
        #pragma unroll
        for (int c = 1; c < 10; ++c) {
            if (lg[c] > mx) { mx2 = mx; mx = lg[c]; am2 = c; }
            else if (lg[c] > mx2) mx2 = lg[c];
        }

        // fp64 cooperative recheck of near-tied pairs (rare). Whole q0-wave
        // recomputes one pair's logits from the 8 fp64 quarter-partials:
        // 8 k's per lane, butterfly-reduce, fp64 argmax overrides am2.
        unsigned long long m = __ballot((j > i) && (mx - mx2 < GAP_THRESH));
        while (m) {
            const int s = __ffsll((unsigned long long)m) - 1; m &= (m - 1);
            const int si = i0 + (s >> 3), sj = j0 + (s & 7);
            double part[10];
            #pragma unroll
            for (int c = 0; c < 10; ++c) part[c] = 0.0;
            const int kb = l * 8;
            #pragma unroll 2
            for (int kk = 0; kk < 8; ++kk) {
                const int k = kb + kk;
                const int ei = si * 512 + k, ej = sj * 512 + k;
                double va = (ca0[ei] + ca1[ei]) + (ca2[ei] + ca3[ei]);
                double vb = (cb0[ej] + cb1p[ej]) + (cb2p[ej] + cb3p[ej]);
                double h = fmax(va + vb, 0.0);
                const float* w = cw2 + k * 10;
                #pragma unroll
                for (int c = 0; c < 10; ++c) part[c] = fma(h, (double)w[c], part[c]);
            }
            #pragma unroll
            for (int off = 32; off > 0; off >>= 1) {
                #pragma unroll
                for (int c = 0; c < 10; ++c) part[c] += __shfl_xor(part[c], off, 64);
            }
            double bmx = part[0] + (double)cb2[0]; int ba = 0;
            #pragma unroll
            for (int c = 1; c < 10; ++c) {
                double v = part[c] + (double)cb2[c];
                if (v > bmx) { bmx = v; ba = c; }   // first-max == np.argmax
            }
            if (l == s) am2 = ba;
        }

        float tf[10]; float ssum = 0.f;
        #pragma unroll
        for (int c = 0; c < 10; ++c) { tf[c] = lg[c] - mx; ssum += __expf(tf[c]); }
        float ls = __logf(ssum);

        if (j > i) {
            const int p = i * 511 - (i * (i - 1)) / 2 + (j - i - 1);
            float* tp = out + TYPES_OFF + p * 10;
            #pragma unroll
            for (int c = 0; c < 10; ++c) tp[c] = tf[c] - ls;
            out[ARGMAX_OFF + p] = (float)am2;
            out[STRENGTH_OFF + p] = 1.0f / (1.0f + __expf(-st));
        }
    }
}

extern "C" void kernel_launch(void* const* d_in, const int* in_sizes, int n_in,
                              void* d_out, int out_size, void* d_ws, size_t ws_size,
                              hipStream_t stream) {
    const float* F   = (const float*)d_in[0];
    const float* cw1 = (const float*)d_in[1];
    const float* cb1 = (const float*)d_in[2];
    const float* cw2 = (const float*)d_in[3];
    const float* cb2 = (const float*)d_in[4];
    const float* sw1 = (const float*)d_in[5];
    const float* sb1 = (const float*)d_in[6];
    const float* sw2 = (const float*)d_in[7];
    const float* sb2 = (const float*)d_in[8];
    float* out = (float*)d_out;

    char* ws = (char*)d_ws;
    double* ca0  = (double*)(ws);
    double* ca1  = (double*)(ws + 2097152);
    double* ca2  = (double*)(ws + 4194304);
    double* ca3  = (double*)(ws + 6291456);
    double* cb0  = (double*)(ws + 8388608);
    double* cb1p = (double*)(ws + 10485760);
    double* cb2p = (double*)(ws + 12582912);
    double* cb3p = (double*)(ws + 14680064);
    float*  sa0  = (float*)(ws + 16777216);
    float*  sa1  = (float*)(ws + 17301504);
    float*  sb0  = (float*)(ws + 17825792);
    float*  sbp1 = (float*)(ws + 18350080);
    float*  cfa  = (float*)(ws + 18874368);
    float*  cfb  = (float*)(ws + 19922944);
    float*  sfa  = (float*)(ws + 20971520);
    float*  sfb  = (float*)(ws + 21495808);

    hipLaunchKernelGGL(proj_kernel, dim3(1280), dim3(256), 0, stream,
                       F, cw1, sw1, cb1, sb1,
                       ca0, ca1, ca2, ca3, cb0, cb1p, cb2p, cb3p,
                       sa0, sa1, sb0, sbp1);
    hipLaunchKernelGGL(combine_kernel, dim3(512), dim3(256), 0, stream,
                       ca0, ca1, ca2, ca3, cb0, cb1p, cb2p, cb3p,
                       sa0, sa1, sb0, sbp1, cfa, cfb, sfa, sfb);
    hipLaunchKernelGGL(pair_kernel, dim3(2080), dim3(256), 0, stream,
                       ca0, ca1, ca2, ca3, cb0, cb1p, cb2p, cb3p,
                       cfa, cfb, sfa, sfb, cw2, cb2, sw2, sb2, out);
}

// Round 7
// 144.938 us; speedup vs baseline: 1.0209x; 1.0209x over previous
//
#include <hip/hip_runtime.h>
#include <math.h>

// Problem constants
#define NN 512
#define DD 512
#define NPAIRS 130816            // 512*511/2
#define TYPES_OFF 0              // [P,10] floats
#define ARGMAX_OFF 1308160      // [P] floats
#define STRENGTH_OFF 1438976    // [P] floats

// fp32 fast-path argmax guard: recompute logits in fp64 when fp32 top-2 gap
// is below this. fp32-path worst-case abs error ~5e-5; realistic rms ~1e-6.
#define GAP_THRESH 2.5e-4f

// ws layout (byte offsets) — classifier K-split-4, strength K-split-2:
//   ca0..ca3 double[512][512] @ 0, 2097152, 4194304, 6291456    (A-part quarters; cb1 folded into q0)
//   cb0..cb3 double[512][512] @ 8388608, 10485760, 12582912, 14680064  (B-part quarters)
//   sa0  float [512][256] @ 16777216   (bias sb1 folded)
//   sa1  float [512][256] @ 17301504
//   sb0  float [512][256] @ 17825792
//   sbp1 float [512][256] @ 18350080
//   cfa  float [512][512] @ 18874368   (= (float)Σca, combine_kernel)
//   cfb  float [512][512] @ 19922944
//   sfa  float [512][256] @ 20971520   (= sa0+sa1)
//   sfb  float [512][256] @ 21495808
// total 22,020,096 bytes
//
// LESSONS LEDGER:
//  R2a: narrower proj n-tiles INCREASE loads-per-FMA; proj time scaled ~1:1
//       with lane-bytes (45.9->76.6 at 2x loads/FMA) => proj is TA/L1
//       return-BW bound on duplicated operand bytes. Fix = fewer bytes/FMA.
//  R2b: no inline asm with "s" constraints in pair loop — scalar
//       materialization + sched fences (VALUBusy 43->26%).
//  R3:  __launch_bounds__(256,6) on pair -> VGPR squeeze -> 217 MB scratch
//       spill traffic (dur 2.5x). Keep (256,4) there.
//  R4:  combine_kernel pre-sums K-split partials once. pair now <42us. WORKED.
//  R5:  K-split 4 raised occupancy 24->37%, duration UNCHANGED => proj is not
//       occupancy-limited (confirms TA-BW theory).
//  R6:  per-thread 4m x 4n: 2.0 B lane-traffic per FMA vs 3.0; block = 4
//       waves stacked in m sharing one B stream (L1 reuse). (R6 submission
//       had a name collision — int b2 vs float4 b2 — never benched.)

__device__ __forceinline__ void fma64_step4(
    const float4& a0, const float4& a1, const float4& a2, const float4& a3,
    const float4& b0, const float4& b1, const float4& b2, const float4& b3,
    double acc[4][4])
{
    const float av[4][4] = {{a0.x,a0.y,a0.z,a0.w},{a1.x,a1.y,a1.z,a1.w},
                            {a2.x,a2.y,a2.z,a2.w},{a3.x,a3.y,a3.z,a3.w}};
    const float bv[4][4] = {{b0.x,b0.y,b0.z,b0.w},{b1.x,b1.y,b1.z,b1.w},
                            {b2.x,b2.y,b2.z,b2.w},{b3.x,b3.y,b3.z,b3.w}};
    #pragma unroll
    for (int kk = 0; kk < 4; ++kk) {
        double bd0 = (double)bv[kk][0], bd1 = (double)bv[kk][1];
        double bd2 = (double)bv[kk][2], bd3 = (double)bv[kk][3];
        #pragma unroll
        for (int rr = 0; rr < 4; ++rr) {
            double ad = (double)av[rr][kk];
            acc[rr][0] = fma(ad, bd0, acc[rr][0]);
            acc[rr][1] = fma(ad, bd1, acc[rr][1]);
            acc[rr][2] = fma(ad, bd2, acc[rr][2]);
            acc[rr][3] = fma(ad, bd3, acc[rr][3]);
        }
    }
}

__device__ __forceinline__ void fma32_step4(
    const float4& a0, const float4& a1, const float4& a2, const float4& a3,
    const float4& b0, const float4& b1, const float4& b2, const float4& b3,
    float acc[4][4])
{
    const float av[4][4] = {{a0.x,a0.y,a0.z,a0.w},{a1.x,a1.y,a1.z,a1.w},
                            {a2.x,a2.y,a2.z,a2.w},{a3.x,a3.y,a3.z,a3.w}};
    const float bv[4][4] = {{b0.x,b0.y,b0.z,b0.w},{b1.x,b1.y,b1.z,b1.w},
                            {b2.x,b2.y,b2.z,b2.w},{b3.x,b3.y,b3.z,b3.w}};
    #pragma unroll
    for (int kk = 0; kk < 4; ++kk) {
        #pragma unroll
        for (int rr = 0; rr < 4; ++rr) {
            #pragma unroll
            for (int cc = 0; cc < 4; ++cc)
                acc[rr][cc] = fmaf(av[rr][kk], bv[kk][cc], acc[rr][cc]);
        }
    }
}

// Barrier-free, LDS-free, atomic-free projection GEMM.
// Classifier (blocks 0..511): block = 64m x 64n x K-quarter; 4 waves stacked
//   in m share one B stream (L1 reuse). Wave = 16m x 64n, thread = 4m x 4n:
//   8 float4 loads per 64 FMAs (was 6 per 32) — 2/3 the lane-bytes.
// Strength (blocks 512..639): block = 64m x 64n x K-half, same thread tile.
// Per-output k-accumulation order identical to R5 (bitwise-same partials).
__global__ __launch_bounds__(256, 2) void proj_kernel(
    const float* __restrict__ F, const float* __restrict__ cw1,
    const float* __restrict__ sw1,
    const float* __restrict__ cb1, const float* __restrict__ sb1,
    double* __restrict__ ca0, double* __restrict__ ca1,
    double* __restrict__ ca2, double* __restrict__ ca3,
    double* __restrict__ cb0, double* __restrict__ cb1p,
    double* __restrict__ cb2p, double* __restrict__ cb3p,
    float* __restrict__ sa0, float* __restrict__ sa1,
    float* __restrict__ sb0, float* __restrict__ sbp1)
{
    const int t = threadIdx.x;
    const int w = t >> 6;                  // wave in block -> m slab
    const int lane = t & 63;
    const int mg = lane >> 4;              // 0..3  (4-row group)
    const int nq = lane & 15;              // 0..15 (4-col group)

    if (blockIdx.x < 512) {
        // ---------------- fp64 classifier projection, K-split 4 ----------------
        const int b  = blockIdx.x;
        const int z  = b & 3;              // K quarter
        const int nt = (b >> 2) & 15;      // 64-col tile over 1024
        const int mt = b >> 6;             // 0..7  (64-row tile)
        const int n  = nt * 64;
        const float* W = (n < 512) ? cw1 : cw1 + 512 * 512;
        const int n0   = (n < 512) ? n : n - 512;
        double* outp;
        if (n < 512) outp = (z == 0) ? ca0 : (z == 1) ? ca1 : (z == 2) ? ca2 : ca3;
        else         outp = (z == 0) ? cb0 : (z == 1) ? cb1p : (z == 2) ? cb2p : cb3p;
        const bool addbias = (z == 0) && (n < 512);

        const int row0 = mt * 64 + w * 16 + mg * 4;
        const int col0 = n0 + nq * 4;
        const float* pa = F + row0 * 512 + z * 128;
        const float* pb = W + (z * 128) * 512 + col0;

        double acc[4][4];
        #pragma unroll
        for (int rr = 0; rr < 4; ++rr)
            #pragma unroll
            for (int cc = 0; cc < 4; ++cc) acc[rr][cc] = 0.0;

        float4 a0 = *(const float4*)(pa);
        float4 a1 = *(const float4*)(pa + 512);
        float4 a2 = *(const float4*)(pa + 1024);
        float4 a3 = *(const float4*)(pa + 1536);
        float4 b0 = *(const float4*)(pb);
        float4 b1 = *(const float4*)(pb + 512);
        float4 b2 = *(const float4*)(pb + 1024);
        float4 b3 = *(const float4*)(pb + 1536);
        for (int s = 0; s < 31; ++s) {     // 32 k4-steps, software-pipelined
            const float* npa = pa + (s + 1) * 4;
            float4 na0 = *(const float4*)(npa);
            float4 na1 = *(const float4*)(npa + 512);
            float4 na2 = *(const float4*)(npa + 1024);
            float4 na3 = *(const float4*)(npa + 1536);
            const float* nb = pb + (s + 1) * 2048;
            float4 nb0 = *(const float4*)(nb);
            float4 nb1 = *(const float4*)(nb + 512);
            float4 nb2 = *(const float4*)(nb + 1024);
            float4 nb3 = *(const float4*)(nb + 1536);
            fma64_step4(a0, a1, a2, a3, b0, b1, b2, b3, acc);
            a0 = na0; a1 = na1; a2 = na2; a3 = na3;
            b0 = nb0; b1 = nb1; b2 = nb2; b3 = nb3;
        }
        fma64_step4(a0, a1, a2, a3, b0, b1, b2, b3, acc);

        #pragma unroll
        for (int rr = 0; rr < 4; ++rr) {
            double v[4];
            #pragma unroll
            for (int cc = 0; cc < 4; ++cc) {
                v[cc] = acc[rr][cc];
                if (addbias) v[cc] += (double)cb1[col0 + cc];
            }
            double* dst = outp + (row0 + rr) * 512 + col0;
            *(double2*)(dst + 0) = make_double2(v[0], v[1]);
            *(double2*)(dst + 2) = make_double2(v[2], v[3]);
        }
    } else {
        // ---------------- fp32 strength projection, K-split 2 ----------------
        const int sbk = blockIdx.x - 512;  // 0..127
        const int z  = sbk & 1;
        const int nt = (sbk >> 1) & 7;     // 64-col tile over 512
        const int mt = sbk >> 4;           // 0..7 (64-row tile)
        const int n  = nt * 64;
        const float* W = (n < 256) ? sw1 : sw1 + 512 * 256;
        const int n0   = (n < 256) ? n : n - 256;
        float* outp    = (n < 256) ? (z ? sa1 : sa0) : (z ? sbp1 : sb0);
        const bool addbias = (z == 0) && (n < 256);

        const int row0 = mt * 64 + w * 16 + mg * 4;
        const int col0 = n0 + nq * 4;
        const float* pa = F + row0 * 512 + z * 256;
        const float* pb = W + (z * 256) * 256 + col0;

        float acc[4][4];
        #pragma unroll
        for (int rr = 0; rr < 4; ++rr)
            #pragma unroll
            for (int cc = 0; cc < 4; ++cc) acc[rr][cc] = 0.f;

        float4 a0 = *(const float4*)(pa);
        float4 a1 = *(const float4*)(pa + 512);
        float4 a2 = *(const float4*)(pa + 1024);
        float4 a3 = *(const float4*)(pa + 1536);
        float4 b0 = *(const float4*)(pb);
        float4 b1 = *(const float4*)(pb + 256);
        float4 b2 = *(const float4*)(pb + 512);
        float4 b3 = *(const float4*)(pb + 768);
        for (int s = 0; s < 63; ++s) {     // 64 k4-steps
            const float* npa = pa + (s + 1) * 4;
            float4 na0 = *(const float4*)(npa);
            float4 na1 = *(const float4*)(npa + 512);
            float4 na2 = *(const float4*)(npa + 1024);
            float4 na3 = *(const float4*)(npa + 1536);
            const float* nb = pb + (s + 1) * 1024;
            float4 nb0 = *(const float4*)(nb);
            float4 nb1 = *(const float4*)(nb + 256);
            float4 nb2 = *(const float4*)(nb + 512);
            float4 nb3 = *(const float4*)(nb + 768);
            fma32_step4(a0, a1, a2, a3, b0, b1, b2, b3, acc);
            a0 = na0; a1 = na1; a2 = na2; a3 = na3;
            b0 = nb0; b1 = nb1; b2 = nb2; b3 = nb3;
        }
        fma32_step4(a0, a1, a2, a3, b0, b1, b2, b3, acc);

        #pragma unroll
        for (int rr = 0; rr < 4; ++rr) {
            float4 v = make_float4(acc[rr][0], acc[rr][1], acc[rr][2], acc[rr][3]);
            if (addbias) {
                v.x += sb1[col0 + 0]; v.y += sb1[col0 + 1];
                v.z += sb1[col0 + 2]; v.w += sb1[col0 + 3];
            }
            *(float4*)(outp + (row0 + rr) * 256 + col0) = v;
        }
    }
}

// Pre-sum the K-split partials ONCE. cfa/cfb = (float)(Σ classifier quarters),
// sfa/sfb = sa0+sa1 etc. ~18 MB read, 3 MB write.
__global__ __launch_bounds__(256) void combine_kernel(
    const double* __restrict__ ca0, const double* __restrict__ ca1,
    const double* __restrict__ ca2, const double* __restrict__ ca3,
    const double* __restrict__ cb0, const double* __restrict__ cb1p,
    const double* __restrict__ cb2p, const double* __restrict__ cb3p,
    const float* __restrict__ sa0, const float* __restrict__ sa1,
    const float* __restrict__ sb0, const float* __restrict__ sbp1,
    float* __restrict__ cfa, float* __restrict__ cfb,
    float* __restrict__ sfa, float* __restrict__ sfb)
{
    const int t = blockIdx.x * 256 + threadIdx.x;     // 0..131071 (512 blocks)
    {   // classifier: double2 unit t of each array (131072 units = 512*512 ele)
        const int e = 2 * t;
        double2 x0 = *(const double2*)(ca0 + e);
        double2 x1 = *(const double2*)(ca1 + e);
        double2 x2 = *(const double2*)(ca2 + e);
        double2 x3 = *(const double2*)(ca3 + e);
        *(float2*)(cfa + e) = make_float2(
            (float)((x0.x + x1.x) + (x2.x + x3.x)),
            (float)((x0.y + x1.y) + (x2.y + x3.y)));
        double2 y0 = *(const double2*)(cb0 + e);
        double2 y1 = *(const double2*)(cb1p + e);
        double2 y2 = *(const double2*)(cb2p + e);
        double2 y3 = *(const double2*)(cb3p + e);
        *(float2*)(cfb + e) = make_float2(
            (float)((y0.x + y1.x) + (y2.x + y3.x)),
            (float)((y0.y + y1.y) + (y2.y + y3.y)));
    }
    if (t < 65536) {   // strength: float4 units (32768 per array)
        const bool second = t >= 32768;
        const int e = (second ? (t - 32768) : t) * 4;
        const float* s0 = second ? sb0 : sa0;
        const float* s1 = second ? sbp1 : sa1;
        float* dst      = second ? sfb : sfa;
        float4 a = *(const float4*)(s0 + e);
        float4 b = *(const float4*)(s1 + e);
        *(float4*)(dst + e) = make_float4(a.x + b.x, a.y + b.y, a.z + b.z, a.w + b.w);
    }
}

// Pair phase: block = 8x8 pair tile, 4 waves = 4 K-quarters, LDS combine.
// Grid: 2080 triangular tiles. Staging is a pure float4 copy from the
// pre-summed cfa/cfb/sfa/sfb. Inner loops read LDS as float4 with
// k-sequential scalar fmaf per channel.
// Argmax exactness preserved by the fp64 cooperative recheck (reads the 8
// fp64 quarter-partials) of pairs whose fp32 top-2 gap < GAP_THRESH.
// NOTE: __launch_bounds__(256,4) — (256,6) spilled 217 MB of scratch (R3).
__global__ __launch_bounds__(256, 4) void pair_kernel(
    const double* __restrict__ ca0, const double* __restrict__ ca1,
    const double* __restrict__ ca2, const double* __restrict__ ca3,
    const double* __restrict__ cb0, const double* __restrict__ cb1p,
    const double* __restrict__ cb2p, const double* __restrict__ cb3p,
    const float* __restrict__ cfa, const float* __restrict__ cfb,
    const float* __restrict__ sfa, const float* __restrict__ sfb,
    const float* __restrict__ cw2, const float* __restrict__ cb2,
    const float* __restrict__ sw2, const float* __restrict__ sb2,
    float* __restrict__ out)
{
    // triangular tile decode: S(bi) = bi*(129-bi)/2
    const int b = blockIdx.x;
    int bi = (int)floorf((129.0f - sqrtf(16641.0f - 8.0f * (float)b)) * 0.5f);
    while ((bi + 1) * (129 - (bi + 1)) / 2 <= b) ++bi;
    while (bi * (129 - bi) / 2 > b) --bi;
    const int bj = bi + (b - bi * (129 - bi) / 2);
    const int i0 = bi * 8, j0 = bj * 8;

    const int t = threadIdx.x;
    const int q  = t >> 6;                               // K-quarter = wave id
    const int qu = __builtin_amdgcn_readfirstlane(q);    // wave-uniform -> s_load bases
    const int l = t & 63;
    const int pi = l >> 3, pj = l & 7;
    const int i = i0 + pi, j = j0 + pj;

    __shared__ __align__(16) float smem[4352];      // 17408 B
    float* sSa = smem;                              // [4*8][68] strength stage
    float* sSb = smem + 2176;
    float* sA  = smem;                              // [4*8][68] classifier stage
    float* sB  = smem + 2176;
    float* lgbuf = smem;                            // [3][64][10]
    float* stbuf = smem + 1920;                     // [3][64]

    // ---------------- strength (fp32), K=64 per quarter ----------------
    #pragma unroll
    for (int u = 0; u < 4; ++u) {
        int idx = u * 256 + t;
        int kq  = idx & 15;
        int row = (idx >> 4) & 7;
        int qq  = (idx >> 7) & 3;
        int arr = idx >> 9;
        int off = (arr ? (j0 + row) : (i0 + row)) * 256 + qq * 64 + kq * 4;
        const float* src = arr ? sfb : sfa;
        float4 v = *(const float4*)(src + off);
        float* dst = (arr ? sSb : sSa) + (qq * 8 + row) * 68 + kq * 4;
        *(float4*)dst = v;
    }
    __syncthreads();
    float accs = 0.f;
    {
        const float* sw2q = sw2 + qu * 64;
        const float* ra = sSa + (q * 8 + pi) * 68;
        const float* rb = sSb + (q * 8 + pj) * 68;
        // 4 partial accumulators break the serial fma chain (strength output
        // has 0.0156 abs tolerance; reassociation safe — argmax unaffected)
        float p0 = 0.f, p1 = 0.f, p2 = 0.f, p3 = 0.f;
        for (int kk = 0; kk < 64; kk += 4) {
            float4 a4 = *(const float4*)(ra + kk);
            float4 b4 = *(const float4*)(rb + kk);
            p0 = fmaf(fmaxf(a4.x + b4.x, 0.f), sw2q[kk + 0], p0);
            p1 = fmaf(fmaxf(a4.y + b4.y, 0.f), sw2q[kk + 1], p1);
            p2 = fmaf(fmaxf(a4.z + b4.z, 0.f), sw2q[kk + 2], p2);
            p3 = fmaf(fmaxf(a4.w + b4.w, 0.f), sw2q[kk + 3], p3);
        }
        accs = (p0 + p1) + (p2 + p3);
    }

    // ---------------- classifier (fp32 fast path), K=128 per quarter ----------------
    float lg[10];
    #pragma unroll
    for (int c = 0; c < 10; ++c) lg[c] = 0.f;

    for (int rnd = 0; rnd < 2; ++rnd) {
        __syncthreads();   // prior reads of sA/sB (or sSa/sSb) done
        // stage 64 k per quarter: pure float4 copy from pre-summed arrays
        #pragma unroll
        for (int u = 0; u < 4; ++u) {
            int idx = u * 256 + t;
            int kq  = idx & 15;               // 16 groups of 4 k
            int row = (idx >> 4) & 7;
            int qq  = (idx >> 7) & 3;
            int arr = idx >> 9;
            int off = (arr ? (j0 + row) : (i0 + row)) * 512 + qq * 128 + rnd * 64 + kq * 4;
            const float* src = arr ? cfb : cfa;
            float4 v = *(const float4*)(src + off);
            float* dst = (arr ? sB : sA) + (qq * 8 + row) * 68 + kq * 4;
            *(float4*)dst = v;
        }
        __syncthreads();
        const float* ra = sA + (q * 8 + pi) * 68;
        const float* rb = sB + (q * 8 + pj) * 68;
        const float* wr = cw2 + (qu * 128 + rnd * 64) * 10;
        for (int kk = 0; kk < 64; kk += 4) {
            float4 ra4 = *(const float4*)(ra + kk);    // ds_read_b128
            float4 rb4 = *(const float4*)(rb + kk);
            float h0 = fmaxf(ra4.x + rb4.x, 0.f);
            float h1 = fmaxf(ra4.y + rb4.y, 0.f);
            float h2 = fmaxf(ra4.z + rb4.z, 0.f);
            float h3 = fmaxf(ra4.w + rb4.w, 0.f);
            const float* w = wr + kk * 10;
            #pragma unroll
            for (int c = 0; c < 10; ++c) lg[c] = fmaf(h0, w[c], lg[c]);
            #pragma unroll
            for (int c = 0; c < 10; ++c) lg[c] = fmaf(h1, w[10 + c], lg[c]);
            #pragma unroll
            for (int c = 0; c < 10; ++c) lg[c] = fmaf(h2, w[20 + c], lg[c]);
            #pragma unroll
            for (int c = 0; c < 10; ++c) lg[c] = fmaf(h3, w[30 + c], lg[c]);
        }
    }

    // ---------------- combine via LDS ----------------
    __syncthreads();
    if (q > 0) {
        float* dst = lgbuf + ((q - 1) * 64 + l) * 10;
        #pragma unroll
        for (int c = 0; c < 10; ++c) dst[c] = lg[c];
        stbuf[(q - 1) * 64 + l] = accs;
    }
    __syncthreads();
    if (q == 0) {
        #pragma unroll
        for (int w = 0; w < 3; ++w) {
            const float* srcb = lgbuf + (w * 64 + l) * 10;
            #pragma unroll
            for (int c = 0; c < 10; ++c) lg[c] += srcb[c];
        }
        float st = accs + stbuf[l] + stbuf[64 + l] + stbuf[128 + l] + sb2[0];

        #pragma unroll
        for (int c = 0; c < 10; ++c) lg[c] += cb2[c];

        // fp32 argmax + top-2 gap
        float mx = lg[0], mx2 = -3.0e38f; int am2 = 0;
        #pragma unroll
        for (int c = 1; c < 10; ++c) {
            if (lg[c] > mx) { mx2 = mx; mx = lg[c]; am2 = c; }
            else if (lg[c] > mx2) mx2 = lg[c];
        }

        // fp64 cooperative recheck of near-tied pairs (rare). Whole q0-wave
        // recomputes one pair's logits from the 8 fp64 quarter-partials:
        // 8 k's per lane, butterfly-reduce, fp64 argmax overrides am2.
        unsigned long long m = __ballot((j > i) && (mx - mx2 < GAP_THRESH));
        while (m) {
            const int s = __ffsll((unsigned long long)m) - 1; m &= (m - 1);
            const int si = i0 + (s >> 3), sj = j0 + (s & 7);
            double part[10];
            #pragma unroll
            for (int c = 0; c < 10; ++c) part[c] = 0.0;
            const int kb = l * 8;
            #pragma unroll 2
            for (int kk = 0; kk < 8; ++kk) {
                const int k = kb + kk;
                const int ei = si * 512 + k, ej = sj * 512 + k;
                double va = (ca0[ei] + ca1[ei]) + (ca2[ei] + ca3[ei]);
                double vb = (cb0[ej] + cb1p[ej]) + (cb2p[ej] + cb3p[ej]);
                double h = fmax(va + vb, 0.0);
                const float* w = cw2 + k * 10;
                #pragma unroll
                for (int c = 0; c < 10; ++c) part[c] = fma(h, (double)w[c], part[c]);
            }
            #pragma unroll
            for (int off = 32; off > 0; off >>= 1) {
                #pragma unroll
                for (int c = 0; c < 10; ++c) part[c] += __shfl_xor(part[c], off, 64);
            }
            double bmx = part[0] + (double)cb2[0]; int ba = 0;
            #pragma unroll
            for (int c = 1; c < 10; ++c) {
                double v = part[c] + (double)cb2[c];
                if (v > bmx) { bmx = v; ba = c; }   // first-max == np.argmax
            }
            if (l == s) am2 = ba;
        }

        float tf[10]; float ssum = 0.f;
        #pragma unroll
        for (int c = 0; c < 10; ++c) { tf[c] = lg[c] - mx; ssum += __expf(tf[c]); }
        float ls = __logf(ssum);

        if (j > i) {
            const int p = i * 511 - (i * (i - 1)) / 2 + (j - i - 1);
            float* tp = out + TYPES_OFF + p * 10;
            #pragma unroll
            for (int c = 0; c < 10; ++c) tp[c] = tf[c] - ls;
            out[ARGMAX_OFF + p] = (float)am2;
            out[STRENGTH_OFF + p] = 1.0f / (1.0f + __expf(-st));
        }
    }
}

extern "C" void kernel_launch(void* const* d_in, const int* in_sizes, int n_in,
                              void* d_out, int out_size, void* d_ws, size_t ws_size,
                              hipStream_t stream) {
    const float* F   = (const float*)d_in[0];
    const float* cw1 = (const float*)d_in[1];
    const float* cb1 = (const float*)d_in[2];
    const float* cw2 = (const float*)d_in[3];
    const float* cb2 = (const float*)d_in[4];
    const float* sw1 = (const float*)d_in[5];
    const float* sb1 = (const float*)d_in[6];
    const float* sw2 = (const float*)d_in[7];
    const float* sb2 = (const float*)d_in[8];
    float* out = (float*)d_out;

    char* ws = (char*)d_ws;
    double* ca0  = (double*)(ws);
    double* ca1  = (double*)(ws + 2097152);
    double* ca2  = (double*)(ws + 4194304);
    double* ca3  = (double*)(ws + 6291456);
    double* cb0  = (double*)(ws + 8388608);
    double* cb1p = (double*)(ws + 10485760);
    double* cb2p = (double*)(ws + 12582912);
    double* cb3p = (double*)(ws + 14680064);
    float*  sa0  = (float*)(ws + 16777216);
    float*  sa1  = (float*)(ws + 17301504);
    float*  sb0  = (float*)(ws + 17825792);
    float*  sbp1 = (float*)(ws + 18350080);
    float*  cfa  = (float*)(ws + 18874368);
    float*  cfb  = (float*)(ws + 19922944);
    float*  sfa  = (float*)(ws + 20971520);
    float*  sfb  = (float*)(ws + 21495808);

    hipLaunchKernelGGL(proj_kernel, dim3(640), dim3(256), 0, stream,
                       F, cw1, sw1, cb1, sb1,
                       ca0, ca1, ca2, ca3, cb0, cb1p, cb2p, cb3p,
                       sa0, sa1, sb0, sbp1);
    hipLaunchKernelGGL(combine_kernel, dim3(512), dim3(256), 0, stream,
                       ca0, ca1, ca2, ca3, cb0, cb1p, cb2p, cb3p,
                       sa0, sa1, sb0, sbp1, cfa, cfb, sfa, sfb);
    hipLaunchKernelGGL(pair_kernel, dim3(2080), dim3(256), 0, stream,
                       ca0, ca1, ca2, ca3, cb0, cb1p, cb2p, cb3p,
                       cfa, cfb, sfa, sfb, cw2, cb2, sw2, sb2, out);
}